// Round 2
// baseline (260.595 us; speedup 1.0000x reference)
//
#include <hip/hip_runtime.h>
#include <hip/hip_bf16.h>

typedef __bf16 bf16x8 __attribute__((ext_vector_type(8)));
typedef float f32x4 __attribute__((ext_vector_type(4)));

#define N 8192
#define D 512
#define NS 64   // spectral components (S)

// workspace layout (bytes) — total ~11.03 MB
#define XBF_OFF 0                          // bf16 Xsw [N][512] (block-swizzled) : 8 MB
#define WT_OFF  (8 * 1024 * 1024)          // bf16 WTsw chunked [256][64s][32i]  : 1 MB
#define SQ_OFF  (WT_OFF + 1024 * 1024)     // f32 sq  [N]      : 32 KB
#define E_OFF   (SQ_OFF + 32 * 1024)       // f32 E   [S][N]   : 2 MB
#define SC_OFF  (E_OFF + N * NS * 4)       // f32 S1, S2       : 8 B

// async global->LDS, 16B per lane; LDS dest = wave-uniform base + lane*16
__device__ __forceinline__ void dma16(const void* g, void* l) {
    __builtin_amdgcn_global_load_lds(
        (const __attribute__((address_space(1))) unsigned int*)g,
        (__attribute__((address_space(3))) unsigned int*)l, 16, 0, 0);
}

// ---------------------------------------------------------------------------
// prep_x: fp32 X -> bf16, row sq-norms, and XOR-swizzle 8-elem blocks within
// each 64-elem group by (row&7) so unpadded LDS tiles are conflict-minimal.
__global__ __launch_bounds__(256) void prep_x(const float* __restrict__ X,
                                              __bf16* __restrict__ Xs,
                                              float* __restrict__ sq) {
    int row = blockIdx.x * 4 + (threadIdx.x >> 6);
    int l = threadIdx.x & 63;
    const float* src = X + (size_t)row * D + l * 8;
    float4 v0 = *(const float4*)src;
    float4 v1 = *(const float4*)(src + 4);
    bf16x8 o;
    o[0] = (__bf16)v0.x; o[1] = (__bf16)v0.y; o[2] = (__bf16)v0.z; o[3] = (__bf16)v0.w;
    o[4] = (__bf16)v1.x; o[5] = (__bf16)v1.y; o[6] = (__bf16)v1.z; o[7] = (__bf16)v1.w;
    int dstb = (l & 56) | ((l ^ row) & 7);          // swizzled 8-elem block index
    *(bf16x8*)(Xs + (size_t)row * D + dstb * 8) = o;
    float acc = v0.x*v0.x + v0.y*v0.y + v0.z*v0.z + v0.w*v0.w
              + v1.x*v1.x + v1.y*v1.y + v1.z*v1.z + v1.w*v1.w;
    for (int off = 32; off > 0; off >>= 1) acc += __shfl_down(acc, off);
    if (l == 0) sq[row] = acc;
}

// ---------------------------------------------------------------------------
// prep_w: W [N][S] fp32 -> chunked bf16 W^T: off = (i>>5)*2048 + s*32 + (i&31)
// so a 128-i chunk is one contiguous 16 KB slab, DMA-copyable linearly to LDS.
__global__ __launch_bounds__(256) void prep_w(const float* __restrict__ W,
                                              __bf16* __restrict__ WTs) {
    __shared__ float T[64][65];
    int i0 = blockIdx.x * 64;
    int t = threadIdx.x;
    for (int j = 0; j < 16; ++j) {
        int idx = t + 256 * j;
        int r = idx >> 6;       // local i
        int c = idx & 63;       // s
        T[c][r] = W[(size_t)(i0 + r) * NS + c];     // coalesced read
    }
    __syncthreads();
    for (int h = 0; h < 2; ++h)
        for (int j = 0; j < 8; ++j) {
            int idx = t + 256 * j;                  // 0..2047
            int s = idx >> 5, il = idx & 31;
            WTs[(size_t)(blockIdx.x * 2 + h) * 2048 + idx] = (__bf16)T[s][h * 32 + il];
        }
}

// ---------------------------------------------------------------------------
// main: grid (64 n-blocks, 16 i-chunks of 512). Per block:
//  - Gram 128x128 tile, BK=64, staged via global_load_lds into unpadded LDS
//  - exp epilogue -> KT[128][136] (bf16) in the SAME LDS region (union)
//  - E[64 s][128 n] += W^T . K via bf16 MFMA, acc over 4 its, one atomicAdd out
__global__ __launch_bounds__(256, 3) void kpca_main(
        const __bf16* __restrict__ Xs, const __bf16* __restrict__ WTs,
        const float* __restrict__ sq, float* __restrict__ Eg) {
    __shared__ __align__(16) char U[34816];          // Xi[0,16K) Xn[16K,32K) | KT[128][136]
    __shared__ __align__(16) __bf16 WT[8192];        // 16 KB chunk of W^T
    __shared__ __align__(16) float sqI[128];

    __bf16* Xi = (__bf16*)U;
    __bf16* Xn = (__bf16*)(U + 16384);
    __bf16* KT = (__bf16*)U;

    const int t = threadIdx.x;
    const int w = t >> 6, l = t & 63;
    const int quad = l >> 4, l15 = l & 15;
    const int wm = w >> 1, wn = w & 1;
    const int n0 = blockIdx.x * 128;
    const int ic0 = blockIdx.y * 512;

    float sqn_v[4];
    for (int nt = 0; nt < 4; ++nt)
        sqn_v[nt] = sq[n0 + wn * 64 + nt * 16 + l15];

    f32x4 accE[4][2];
    for (int st = 0; st < 4; ++st)
        for (int n2 = 0; n2 < 2; ++n2)
            accE[st][n2] = (f32x4){0.f, 0.f, 0.f, 0.f};

    for (int it = 0; it < 4; ++it) {
        const int i0 = ic0 + it * 128;
        __syncthreads();   // prev E-phase reads (WT + KT/union) complete

        // W^T chunk DMA: 16 KB contiguous, 4 instrs/wave
        {
            const __bf16* gb = WTs + (size_t)(i0 >> 5) * 2048;
            for (int j = 0; j < 4; ++j) {
                int off = (w * 4 + j) * 512 + l * 8;
                dma16(gb + off, WT + off);
            }
        }
        if (t < 128) sqI[t] = sq[i0 + t];

        f32x4 accG[4][4];
        for (int mt = 0; mt < 4; ++mt)
            for (int nt = 0; nt < 4; ++nt)
                accG[mt][nt] = (f32x4){0.f, 0.f, 0.f, 0.f};

        for (int kc8 = 0; kc8 < 8; ++kc8) {
            const int kc = kc8 * 64;
            if (kc8) __syncthreads();       // prior frag reads done before overwrite
            // stage Xi/Xn [128][64] (swizzled blocks), 4+4 DMA per wave
            for (int j = 0; j < 4; ++j) {
                int r  = (w * 4 + j) * 8 + (l >> 3);
                int lo = (w * 4 + j) * 512 + l * 8;
                int gc = kc + (l & 7) * 8;
                dma16(Xs + (size_t)(i0 + r) * D + gc, Xi + lo);
                dma16(Xs + (size_t)(n0 + r) * D + gc, Xn + lo);
            }
            __syncthreads();                // drain DMA
            for (int kh = 0; kh < 2; ++kh) {
                bf16x8 a[4], b[4];
                int swz = ((kh * 4 + quad) ^ (l15 & 7)) * 8;
                for (int mt = 0; mt < 4; ++mt)
                    a[mt] = *(const bf16x8*)(Xi + (wm * 64 + mt * 16 + l15) * 64 + swz);
                for (int nt = 0; nt < 4; ++nt)
                    b[nt] = *(const bf16x8*)(Xn + (wn * 64 + nt * 16 + l15) * 64 + swz);
                for (int mt = 0; mt < 4; ++mt)
                    for (int nt = 0; nt < 4; ++nt)
                        accG[mt][nt] = __builtin_amdgcn_mfma_f32_16x16x32_bf16(
                            a[mt], b[nt], accG[mt][nt], 0, 0, 0);
            }
        }
        __syncthreads();   // Gram frag reads done before KT overwrites union

        // epilogue: d2 -> exp -> bf16 KT[n][i] (C layout: col(n)=l15, row(i)=quad*4+r)
        for (int mt = 0; mt < 4; ++mt) {
            int ibase = wm * 64 + mt * 16 + quad * 4;
            f32x4 si = *(const f32x4*)&sqI[ibase];
            for (int nt = 0; nt < 4; ++nt) {
                int nloc = wn * 64 + nt * 16 + l15;
                float sn = sqn_v[nt];
                union { __bf16 h[4]; uint2 u; } pk;
                for (int r = 0; r < 4; ++r) {
                    float d2 = si[r] + sn - 2.0f * accG[mt][nt][r];
                    pk.h[r] = (__bf16)__expf(d2 * -9.765625e-4f);   // exp(-d2/1024)
                }
                *(uint2*)(KT + nloc * 136 + ibase) = pk.u;
            }
        }
        __syncthreads();   // KT visible (WT DMA drained at earlier barriers)

        // E[s][n] += sum_i WT[s][i] * KT[n][i]; wave w owns n in [w*32, w*32+32)
        for (int kc2 = 0; kc2 < 4; ++kc2) {
            bf16x8 aw[4], bk[2];
            for (int st = 0; st < 4; ++st)
                aw[st] = *(const bf16x8*)(WT + kc2 * 2048 + (st * 16 + l15) * 32 + quad * 8);
            for (int n2 = 0; n2 < 2; ++n2)
                bk[n2] = *(const bf16x8*)(KT + (w * 32 + n2 * 16 + l15) * 136 + kc2 * 32 + quad * 8);
            for (int st = 0; st < 4; ++st)
                for (int n2 = 0; n2 < 2; ++n2)
                    accE[st][n2] = __builtin_amdgcn_mfma_f32_16x16x32_bf16(
                        aw[st], bk[n2], accE[st][n2], 0, 0, 0);
        }
    }

    for (int st = 0; st < 4; ++st)
        for (int n2 = 0; n2 < 2; ++n2)
            for (int r = 0; r < 4; ++r) {
                int s = st * 16 + quad * 4 + r;
                int n = n0 + w * 32 + n2 * 16 + l15;
                atomicAdd(Eg + (size_t)s * N + n, accE[st][n2][r]);
            }
}

// ---------------------------------------------------------------------------
__global__ __launch_bounds__(256) void loss_kernel(const float* __restrict__ Eg,
                                                   const float* __restrict__ W,
                                                   const float* __restrict__ lam,
                                                   float* __restrict__ Sacc) {
    int s = blockIdx.x;
    int t = threadIdx.x;
    float a1 = 0.f, a2 = 0.f;
    for (int n = t; n < N; n += 256) {
        float e = Eg[(size_t)s * N + n];
        a1 += e * e;
        a2 += e * W[(size_t)n * NS + s];
    }
    for (int off = 32; off > 0; off >>= 1) {
        a1 += __shfl_down(a1, off);
        a2 += __shfl_down(a2, off);
    }
    __shared__ float r1[4], r2[4];
    int wv = t >> 6, ln = t & 63;
    if (ln == 0) { r1[wv] = a1; r2[wv] = a2; }
    __syncthreads();
    if (t == 0) {
        atomicAdd(Sacc + 0, lam[s] * (r1[0] + r1[1] + r1[2] + r1[3]));
        atomicAdd(Sacc + 1, r2[0] + r2[1] + r2[2] + r2[3]);
    }
}

__global__ void finalize(const float* __restrict__ Sacc, float* __restrict__ out) {
    float L = 0.5f * (Sacc[1] - Sacc[0]);   // loss1=-S1/2, loss2=S2/2 (eta=1)
    out[0] = L + 0.05f * L * L;             // C_STAB/2 = 0.05
}

// ---------------------------------------------------------------------------
extern "C" void kernel_launch(void* const* d_in, const int* in_sizes, int n_in,
                              void* d_out, int out_size, void* d_ws, size_t ws_size,
                              hipStream_t stream) {
    const float* X   = (const float*)d_in[0];   // [8192][512]
    const float* W   = (const float*)d_in[1];   // [8192][64]
    const float* lam = (const float*)d_in[2];   // [64]
    float* out = (float*)d_out;
    char* ws = (char*)d_ws;
    __bf16* Xs  = (__bf16*)(ws + XBF_OFF);
    __bf16* WTs = (__bf16*)(ws + WT_OFF);
    float* sq   = (float*)(ws + SQ_OFF);
    float* Eg   = (float*)(ws + E_OFF);
    float* Sacc = (float*)(ws + SC_OFF);

    hipMemsetAsync(Eg, 0, (size_t)N * NS * 4 + 8, stream);   // E + S1/S2
    prep_x<<<N / 4, 256, 0, stream>>>(X, Xs, sq);
    prep_w<<<N / 64, 256, 0, stream>>>(W, WTs);
    kpca_main<<<dim3(64, 16), 256, 0, stream>>>(Xs, WTs, sq, Eg);
    loss_kernel<<<NS, 256, 0, stream>>>(Eg, W, lam, Sacc);
    finalize<<<1, 1, 0, stream>>>(Sacc, out);
}

// Round 3
// 178.232 us; speedup vs baseline: 1.4621x; 1.4621x over previous
//
#include <hip/hip_runtime.h>
#include <hip/hip_bf16.h>

typedef __bf16 bf16x8 __attribute__((ext_vector_type(8)));
typedef float f32x4 __attribute__((ext_vector_type(4)));
typedef long longx2 __attribute__((ext_vector_type(2)));

#define N 8192
#define D 512
#define NS 64   // spectral components (S)

// workspace layout (bytes) — ~7.1 MB
#define XS_OFF 0                           // fp8 X  [N][512 B] (permuted+swizzled) : 4 MB
#define WT_OFF (4 * 1024 * 1024)           // bf16 WTsw chunked [256][64s][32i]     : 1 MB
#define SQ_OFF (WT_OFF + 1024 * 1024)      // f32 sq [N]  : 32 KB
#define E_OFF  (SQ_OFF + 32 * 1024)        // f32 E [S][N]: 2 MB
#define SC_OFF (E_OFF + N * NS * 4)        // f32 S1, S2  : 8 B

// ---------------------------------------------------------------------------
// prep_x: fp32 X -> fp8 e4m3, row sq-norms (fp32).
// Per 64-B k-group: 16-B blocks permuted so logical k = kh*32 + q*8 + j is
// stored at block q (both kh halves adjacent -> frag reads are one b128),
// and blocks XOR-swizzled by (row&3) for conflict-free unpadded LDS tiles.
__global__ __launch_bounds__(256) void prep_x(const float* __restrict__ X,
                                              unsigned char* __restrict__ Xs,
                                              float* __restrict__ sq) {
    int row = blockIdx.x * 4 + (threadIdx.x >> 6);
    int l = threadIdx.x & 63;
    const float* src = X + (size_t)row * D + l * 8;
    float4 v0 = *(const float4*)src;
    float4 v1 = *(const float4*)(src + 4);
    int w0 = __builtin_amdgcn_cvt_pk_fp8_f32(v0.x, v0.y, 0, false);
    w0     = __builtin_amdgcn_cvt_pk_fp8_f32(v0.z, v0.w, w0, true);
    int w1 = __builtin_amdgcn_cvt_pk_fp8_f32(v1.x, v1.y, 0, false);
    w1     = __builtin_amdgcn_cvt_pk_fp8_f32(v1.z, v1.w, w1, true);
    // lane covers logical k in [8l, 8l+8): group g=l>>3, half kh=(l>>2)&1, q=l&3
    int g = l >> 3, kh = (l >> 2) & 1, q = l & 3;
    int pos = g * 64 + ((q ^ (row & 3)) << 4) + (kh << 3);
    uint2 pk = make_uint2((unsigned)w0, (unsigned)w1);
    *(uint2*)(Xs + (size_t)row * 512 + pos) = pk;
    float acc = v0.x*v0.x + v0.y*v0.y + v0.z*v0.z + v0.w*v0.w
              + v1.x*v1.x + v1.y*v1.y + v1.z*v1.z + v1.w*v1.w;
    for (int off = 32; off > 0; off >>= 1) acc += __shfl_down(acc, off);
    if (l == 0) sq[row] = acc;
}

// ---------------------------------------------------------------------------
// prep_w: W [N][S] fp32 -> chunked bf16 W^T: off = (i>>5)*2048 + s*32 + (i&31)
__global__ __launch_bounds__(256) void prep_w(const float* __restrict__ W,
                                              __bf16* __restrict__ WTs) {
    __shared__ float T[64][65];
    int i0 = blockIdx.x * 64;
    int t = threadIdx.x;
    for (int j = 0; j < 16; ++j) {
        int idx = t + 256 * j;
        int r = idx >> 6;       // local i
        int c = idx & 63;       // s
        T[c][r] = W[(size_t)(i0 + r) * NS + c];     // coalesced read
    }
    __syncthreads();
    for (int h = 0; h < 2; ++h)
        for (int j = 0; j < 8; ++j) {
            int idx = t + 256 * j;                  // 0..2047
            int s = idx >> 5, il = idx & 31;
            WTs[(size_t)(blockIdx.x * 2 + h) * 2048 + idx] = (__bf16)T[s][h * 32 + il];
        }
}

// ---------------------------------------------------------------------------
// main: grid (64 n-blocks, 8 i-chunks of 1024). Per block, 8 its of 128 i:
//  - Gram 128x128 tile in fp8 (mfma_16x16x32_fp8_fp8), BK=64, vector-load
//    staging through VGPRs (L1-cached re-reads), unpadded swizzled LDS tiles
//  - exp epilogue -> KT bf16 [128][136] in the SAME LDS region (union)
//  - E[64 s][128 n] += W^T . K via bf16 MFMA; acc over its; one atomicAdd out
__global__ __launch_bounds__(256, 2) void kpca_main(
        const unsigned char* __restrict__ Xs, const __bf16* __restrict__ WTs,
        const float* __restrict__ sq, float* __restrict__ Eg) {
    __shared__ __align__(16) unsigned char U[34816];  // Xi[0,8K) Xn[8K,16K) | KT bf16[128][136]
    __shared__ __align__(16) __bf16 WT[8192];         // 16 KB chunk of W^T
    __shared__ __align__(16) float sqI[128];

    unsigned char* Xi = U;
    unsigned char* Xn = U + 8192;
    __bf16* KT = (__bf16*)U;

    const int t = threadIdx.x;
    const int w = t >> 6, l = t & 63;
    const int quad = l >> 4, l15 = l & 15;
    const int wm = w >> 1, wn = w & 1;
    const int n0 = blockIdx.x * 128;
    const int ic0 = blockIdx.y * 1024;
    // swizzled 16-B block offset for this lane's frag reads (row&3 == l15&3)
    const int fro = (quad ^ (l15 & 3)) << 4;

    float sqn_v[4];
    for (int nt = 0; nt < 4; ++nt)
        sqn_v[nt] = sq[n0 + wn * 64 + nt * 16 + l15];

    f32x4 accE[4][2];
    for (int st = 0; st < 4; ++st)
        for (int n2 = 0; n2 < 2; ++n2)
            accE[st][n2] = (f32x4){0.f, 0.f, 0.f, 0.f};

    const int c0 = t, c1 = t + 256;           // staging chunk ids (16 B each)
    const int r0 = c0 >> 2, b0 = (c0 & 3) * 16;
    const int r1 = c1 >> 2, b1 = (c1 & 3) * 16;

    for (int it = 0; it < 8; ++it) {
        const int i0 = ic0 + it * 128;

        // W^T chunk: global loads into VGPRs (before barrier), store after
        uint4 wv[4];
        const char* wb = (const char*)(WTs + (size_t)(i0 >> 5) * 2048);
        for (int j = 0; j < 4; ++j)
            wv[j] = *(const uint4*)(wb + (t + 256 * j) * 16);
        __syncthreads();   // prev E-phase reads (WT + KT/union) complete
        for (int j = 0; j < 4; ++j)
            *(uint4*)((char*)WT + (t + 256 * j) * 16) = wv[j];
        if (t < 128) sqI[t] = sq[i0 + t];

        f32x4 accG[4][4];
        for (int mt = 0; mt < 4; ++mt)
            for (int nt = 0; nt < 4; ++nt)
                accG[mt][nt] = (f32x4){0.f, 0.f, 0.f, 0.f};

        for (int kc8 = 0; kc8 < 8; ++kc8) {
            const int kc = kc8 * 64;
            // global loads first (no LDS hazard -> overlap prev iter's drain)
            uint4 xi0 = *(const uint4*)(Xs + (size_t)(i0 + r0) * 512 + kc + b0);
            uint4 xi1 = *(const uint4*)(Xs + (size_t)(i0 + r1) * 512 + kc + b1);
            uint4 xn0 = *(const uint4*)(Xs + (size_t)(n0 + r0) * 512 + kc + b0);
            uint4 xn1 = *(const uint4*)(Xs + (size_t)(n0 + r1) * 512 + kc + b1);
            if (kc8) __syncthreads();          // prior frag reads done
            *(uint4*)(Xi + c0 * 16) = xi0;     // verbatim row copy (swizzle kept)
            *(uint4*)(Xi + c1 * 16) = xi1;
            *(uint4*)(Xn + c0 * 16) = xn0;
            *(uint4*)(Xn + c1 * 16) = xn1;
            __syncthreads();
            longx2 a[4], b[4];                 // [0]=k 0..31 half, [1]=k 32..63 half
            for (int mt = 0; mt < 4; ++mt)
                a[mt] = *(const longx2*)(Xi + (wm * 64 + mt * 16 + l15) * 64 + fro);
            for (int nt = 0; nt < 4; ++nt)
                b[nt] = *(const longx2*)(Xn + (wn * 64 + nt * 16 + l15) * 64 + fro);
            for (int mt = 0; mt < 4; ++mt)
                for (int nt = 0; nt < 4; ++nt)
                    accG[mt][nt] = __builtin_amdgcn_mfma_f32_16x16x32_fp8_fp8(
                        a[mt][0], b[nt][0], accG[mt][nt], 0, 0, 0);
            for (int mt = 0; mt < 4; ++mt)
                for (int nt = 0; nt < 4; ++nt)
                    accG[mt][nt] = __builtin_amdgcn_mfma_f32_16x16x32_fp8_fp8(
                        a[mt][1], b[nt][1], accG[mt][nt], 0, 0, 0);
        }
        __syncthreads();   // Gram frag reads done before KT overwrites union

        // epilogue: d2 -> exp -> bf16 KT[n][i] (C layout: col(n)=l15, row(i)=quad*4+r)
        for (int mt = 0; mt < 4; ++mt) {
            int ibase = wm * 64 + mt * 16 + quad * 4;
            f32x4 si = *(const f32x4*)&sqI[ibase];
            for (int nt = 0; nt < 4; ++nt) {
                int nloc = wn * 64 + nt * 16 + l15;
                float sn = sqn_v[nt];
                union { __bf16 h[4]; uint2 u; } pk;
                for (int r = 0; r < 4; ++r) {
                    float d2 = si[r] + sn - 2.0f * accG[mt][nt][r];
                    pk.h[r] = (__bf16)__expf(d2 * -9.765625e-4f);   // exp(-d2/1024)
                }
                *(uint2*)(KT + nloc * 136 + ibase) = pk.u;
            }
        }
        __syncthreads();   // KT + WT visible

        // E[s][n] += sum_i WT[s][i] * KT[n][i]; wave w owns n in [w*32, w*32+32)
        for (int kc2 = 0; kc2 < 4; ++kc2) {
            bf16x8 aw[4], bk[2];
            for (int st = 0; st < 4; ++st)
                aw[st] = *(const bf16x8*)(WT + kc2 * 2048 + (st * 16 + l15) * 32 + quad * 8);
            for (int n2 = 0; n2 < 2; ++n2)
                bk[n2] = *(const bf16x8*)(KT + (w * 32 + n2 * 16 + l15) * 136 + kc2 * 32 + quad * 8);
            for (int st = 0; st < 4; ++st)
                for (int n2 = 0; n2 < 2; ++n2)
                    accE[st][n2] = __builtin_amdgcn_mfma_f32_16x16x32_bf16(
                        aw[st], bk[n2], accE[st][n2], 0, 0, 0);
        }
    }

    for (int st = 0; st < 4; ++st)
        for (int n2 = 0; n2 < 2; ++n2)
            for (int r = 0; r < 4; ++r) {
                int s = st * 16 + quad * 4 + r;
                int n = n0 + w * 32 + n2 * 16 + l15;
                atomicAdd(Eg + (size_t)s * N + n, accE[st][n2][r]);
            }
}

// ---------------------------------------------------------------------------
__global__ __launch_bounds__(256) void loss_kernel(const float* __restrict__ Eg,
                                                   const float* __restrict__ W,
                                                   const float* __restrict__ lam,
                                                   float* __restrict__ Sacc) {
    int s = blockIdx.x;
    int t = threadIdx.x;
    float a1 = 0.f, a2 = 0.f;
    for (int n = t; n < N; n += 256) {
        float e = Eg[(size_t)s * N + n];
        a1 += e * e;
        a2 += e * W[(size_t)n * NS + s];
    }
    for (int off = 32; off > 0; off >>= 1) {
        a1 += __shfl_down(a1, off);
        a2 += __shfl_down(a2, off);
    }
    __shared__ float r1[4], r2[4];
    int wv = t >> 6, ln = t & 63;
    if (ln == 0) { r1[wv] = a1; r2[wv] = a2; }
    __syncthreads();
    if (t == 0) {
        atomicAdd(Sacc + 0, lam[s] * (r1[0] + r1[1] + r1[2] + r1[3]));
        atomicAdd(Sacc + 1, r2[0] + r2[1] + r2[2] + r2[3]);
    }
}

__global__ void finalize(const float* __restrict__ Sacc, float* __restrict__ out) {
    float L = 0.5f * (Sacc[1] - Sacc[0]);   // loss1=-S1/2, loss2=S2/2 (eta=1)
    out[0] = L + 0.05f * L * L;             // C_STAB/2 = 0.05
}

// ---------------------------------------------------------------------------
extern "C" void kernel_launch(void* const* d_in, const int* in_sizes, int n_in,
                              void* d_out, int out_size, void* d_ws, size_t ws_size,
                              hipStream_t stream) {
    const float* X   = (const float*)d_in[0];   // [8192][512]
    const float* W   = (const float*)d_in[1];   // [8192][64]
    const float* lam = (const float*)d_in[2];   // [64]
    float* out = (float*)d_out;
    char* ws = (char*)d_ws;
    unsigned char* Xs = (unsigned char*)(ws + XS_OFF);
    __bf16* WTs = (__bf16*)(ws + WT_OFF);
    float* sq   = (float*)(ws + SQ_OFF);
    float* Eg   = (float*)(ws + E_OFF);
    float* Sacc = (float*)(ws + SC_OFF);

    hipMemsetAsync(Eg, 0, (size_t)N * NS * 4 + 8, stream);   // E + S1/S2
    prep_x<<<N / 4, 256, 0, stream>>>(X, Xs, sq);
    prep_w<<<N / 64, 256, 0, stream>>>(W, WTs);
    kpca_main<<<dim3(64, 8), 256, 0, stream>>>(Xs, WTs, sq, Eg);
    loss_kernel<<<NS, 256, 0, stream>>>(Eg, W, lam, Sacc);
    finalize<<<1, 1, 0, stream>>>(Sacc, out);
}